// Round 1
// baseline (386.202 us; speedup 1.0000x reference)
//
#include <hip/hip_runtime.h>
#include <hip/hip_bf16.h>

// SRU: T=4096 B=8 D=H=512, two layers.
// Pipeline per layer: bf16 GEMM (U = in @ W^T) -> chunked parallel linear scan -> highway epilogue.

#define T_DIM 4096
#define B_DIM 8
#define H_DIM 512
#define M_DIM (T_DIM * B_DIM)   // 32768 rows
#define N3H 1536                // 3*H
#define K_DIM 512
#define NCHUNK 64
#define CLEN (T_DIM / NCHUNK)   // 64
#define NCHAIN (B_DIM * H_DIM)  // 4096

typedef __attribute__((ext_vector_type(8))) short s16x8;   // 8 bf16 (4 VGPRs)
typedef __attribute__((ext_vector_type(4))) float f32x4;
typedef unsigned short ushort_t;
typedef unsigned int uint_t;

__device__ __forceinline__ float bf2f(ushort_t u) {
    return __uint_as_float(((uint_t)u) << 16);
}
__device__ __forceinline__ ushort_t f2bf(float f) {
    uint_t u = __float_as_uint(f);
    u += 0x7FFFu + ((u >> 16) & 1u);   // RNE
    return (ushort_t)(u >> 16);
}
__device__ __forceinline__ float sigm(float z) {
    return 1.0f / (1.0f + __expf(-z));
}
__device__ __forceinline__ float tanh_fast(float z) {
    float e = __expf(2.0f * z);
    return (e - 1.0f) / (e + 1.0f);
}

// ---------------- fp32 -> bf16 convert (vectorized) ----------------
__global__ void cvt_f32_bf16(const float* __restrict__ in, ushort_t* __restrict__ out, int n4) {
    int i = blockIdx.x * blockDim.x + threadIdx.x;
    if (i < n4) {
        float4 v = reinterpret_cast<const float4*>(in)[i];
        ushort4 o;
        o.x = f2bf(v.x); o.y = f2bf(v.y); o.z = f2bf(v.z); o.w = f2bf(v.w);
        reinterpret_cast<ushort4*>(out)[i] = o;
    }
}

// ---------------- bf16 GEMM, B-transposed input (m97 structure) ----------------
// C[M][N] = A[M][K] * B[N][K]^T, all bf16 (bits as ushort), C written bf16.
// 128x128 tile, BK=64, 256 threads (4 waves as 2x2, each wave 64x64 via 4x4 frags of 16x16x32).
__global__ void gemm_bt(const ushort_t* __restrict__ A, const ushort_t* __restrict__ Bm,
                        ushort_t* __restrict__ C, int M, int N, int K) {
    __shared__ ushort_t As[128 * 64];
    __shared__ ushort_t Bs[128 * 64];
    const int ntn = N >> 7;
    const int tm = blockIdx.x / ntn;
    const int tn = blockIdx.x % ntn;
    const int row0 = tm << 7, col0 = tn << 7;
    const int tid = threadIdx.x;
    const int wave = tid >> 6, lane = tid & 63;
    const int frow = (wave >> 1) << 6;   // wave row offset: 0/64
    const int fcol = (wave & 1) << 6;    // wave col offset: 0/64
    f32x4 acc[4][4] = {};

    const int lr = lane >> 3;            // 0..7 row within 8-row segment
    const int lc = (lane & 7) << 3;      // element col within row (8 elems = 16B)

    for (int k0 = 0; k0 < K; k0 += 64) {
        // stage A-tile and B-tile (128x64 bf16 each) via global_load_lds width=16
#pragma unroll
        for (int i = 0; i < 4; ++i) {
            const int r = i * 32 + wave * 8;   // wave-uniform segment base row
            const ushort_t* ga = A + (size_t)(row0 + r + lr) * K + k0 + lc;
            const ushort_t* gb = Bm + (size_t)(col0 + r + lr) * K + k0 + lc;
            __builtin_amdgcn_global_load_lds(
                (const __attribute__((address_space(1))) void*)ga,
                (__attribute__((address_space(3))) void*)&As[r * 64], 16, 0, 0);
            __builtin_amdgcn_global_load_lds(
                (const __attribute__((address_space(1))) void*)gb,
                (__attribute__((address_space(3))) void*)&Bs[r * 64], 16, 0, 0);
        }
        __syncthreads();
#pragma unroll
        for (int kk = 0; kk < 64; kk += 32) {
            const int kb = kk + ((lane >> 4) << 3);
            s16x8 af[4], bfr[4];
#pragma unroll
            for (int m = 0; m < 4; ++m)
                af[m] = *reinterpret_cast<const s16x8*>(&As[(frow + m * 16 + (lane & 15)) * 64 + kb]);
#pragma unroll
            for (int n = 0; n < 4; ++n)
                bfr[n] = *reinterpret_cast<const s16x8*>(&Bs[(fcol + n * 16 + (lane & 15)) * 64 + kb]);
#pragma unroll
            for (int m = 0; m < 4; ++m)
#pragma unroll
                for (int n = 0; n < 4; ++n)
                    acc[m][n] = __builtin_amdgcn_mfma_f32_16x16x32_bf16(af[m], bfr[n], acc[m][n], 0, 0, 0);
        }
        __syncthreads();
    }
    // epilogue: C/D layout col=lane&15, row=(lane>>4)*4+v  (m89-verified)
    const int crow = (lane >> 4) << 2;
    const int ccol = lane & 15;
#pragma unroll
    for (int m = 0; m < 4; ++m)
#pragma unroll
        for (int n = 0; n < 4; ++n)
#pragma unroll
            for (int v = 0; v < 4; ++v)
                C[(size_t)(row0 + frow + m * 16 + crow + v) * N + (col0 + fcol + n * 16 + ccol)] =
                    f2bf(acc[m][n][v]);
}

// ---------------- scan pass A: per-chunk summaries (A=prod f, B=local c) ----------------
// grid: B_DIM*NCHUNK blocks, 128 threads; thread handles 4 h-values of one (b, chunk).
__global__ void scan_summary(const ushort_t* __restrict__ U, const float* __restrict__ bias,
                             float* __restrict__ Sa, float* __restrict__ Sb) {
    const int b = blockIdx.x / NCHUNK;
    const int chunk = blockIdx.x % NCHUNK;
    const int h = threadIdx.x << 2;
    float fb[4];
#pragma unroll
    for (int j = 0; j < 4; ++j) fb[j] = bias[h + j];
    float Aa[4] = {1.f, 1.f, 1.f, 1.f};
    float Bb[4] = {0.f, 0.f, 0.f, 0.f};
    for (int s = 0; s < CLEN; ++s) {
        const ushort_t* rp = U + (size_t)((chunk * CLEN + s) * B_DIM + b) * N3H;
        ushort4 xt = *reinterpret_cast<const ushort4*>(rp + h);
        ushort4 fp = *reinterpret_cast<const ushort4*>(rp + H_DIM + h);
        ushort_t xts[4] = {xt.x, xt.y, xt.z, xt.w};
        ushort_t fps[4] = {fp.x, fp.y, fp.z, fp.w};
#pragma unroll
        for (int j = 0; j < 4; ++j) {
            float f = sigm(bf2f(fps[j]) + fb[j]);
            Aa[j] *= f;
            Bb[j] = f * Bb[j] + (1.f - f) * bf2f(xts[j]);
        }
    }
    const int cb = chunk * NCHAIN + b * H_DIM + h;
#pragma unroll
    for (int j = 0; j < 4; ++j) { Sa[cb + j] = Aa[j]; Sb[cb + j] = Bb[j]; }
}

// ---------------- scan pass B: combine chunk summaries per chain ----------------
__global__ void scan_fixup(const float* __restrict__ Sa, const float* __restrict__ Sb,
                           float* __restrict__ centry, float* __restrict__ clast) {
    const int chain = blockIdx.x * blockDim.x + threadIdx.x;  // 4096 chains
    float c = 0.f;
    for (int k = 0; k < NCHUNK; ++k) {
        centry[k * NCHAIN + chain] = c;
        c = Sa[k * NCHAIN + chain] * c + Sb[k * NCHAIN + chain];
    }
    if (clast) clast[chain] = c;   // chain = b*H + h -> [B][H]
}

// ---------------- scan pass C: apply with correct entry c + highway epilogue ----------------
template <bool IN_BF16, bool OUT_BF16>
__global__ void scan_apply(const ushort_t* __restrict__ U, const float* __restrict__ bias,
                           const float* __restrict__ centry,
                           const void* __restrict__ xin, void* __restrict__ hout) {
    const int b = blockIdx.x / NCHUNK;
    const int chunk = blockIdx.x % NCHUNK;
    const int h = threadIdx.x << 2;
    const int cb = chunk * NCHAIN + b * H_DIM + h;
    float cc[4], fb[4], rb[4];
#pragma unroll
    for (int j = 0; j < 4; ++j) {
        cc[j] = centry[cb + j];
        fb[j] = bias[h + j];
        rb[j] = bias[H_DIM + h + j];
    }
    for (int s = 0; s < CLEN; ++s) {
        const size_t row = (size_t)((chunk * CLEN + s) * B_DIM + b);
        const ushort_t* rp = U + row * N3H;
        ushort4 xt = *reinterpret_cast<const ushort4*>(rp + h);
        ushort4 fp = *reinterpret_cast<const ushort4*>(rp + H_DIM + h);
        ushort4 rr = *reinterpret_cast<const ushort4*>(rp + 2 * H_DIM + h);
        ushort_t xts[4] = {xt.x, xt.y, xt.z, xt.w};
        ushort_t fps[4] = {fp.x, fp.y, fp.z, fp.w};
        ushort_t rps[4] = {rr.x, rr.y, rr.z, rr.w};
        float xv[4];
        if (IN_BF16) {
            ushort4 xi = *reinterpret_cast<const ushort4*>((const ushort_t*)xin + row * H_DIM + h);
            xv[0] = bf2f(xi.x); xv[1] = bf2f(xi.y); xv[2] = bf2f(xi.z); xv[3] = bf2f(xi.w);
        } else {
            float4 xi = *reinterpret_cast<const float4*>((const float*)xin + row * H_DIM + h);
            xv[0] = xi.x; xv[1] = xi.y; xv[2] = xi.z; xv[3] = xi.w;
        }
        float hv[4];
#pragma unroll
        for (int j = 0; j < 4; ++j) {
            float f = sigm(bf2f(fps[j]) + fb[j]);
            cc[j] = f * cc[j] + (1.f - f) * bf2f(xts[j]);
            float r = sigm(bf2f(rps[j]) + rb[j]);
            hv[j] = r * tanh_fast(cc[j]) + (1.f - r) * xv[j];
        }
        if (OUT_BF16) {
            ushort4 o;
            o.x = f2bf(hv[0]); o.y = f2bf(hv[1]); o.z = f2bf(hv[2]); o.w = f2bf(hv[3]);
            *reinterpret_cast<ushort4*>((ushort_t*)hout + row * H_DIM + h) = o;
        } else {
            float4 o;
            o.x = hv[0]; o.y = hv[1]; o.z = hv[2]; o.w = hv[3];
            *reinterpret_cast<float4*>((float*)hout + row * H_DIM + h) = o;
        }
    }
}

extern "C" void kernel_launch(void* const* d_in, const int* in_sizes, int n_in,
                              void* d_out, int out_size, void* d_ws, size_t ws_size,
                              hipStream_t stream) {
    (void)in_sizes; (void)n_in; (void)out_size; (void)ws_size;
    const float* x  = (const float*)d_in[0];   // [T,B,512]
    const float* W0 = (const float*)d_in[1];   // [1536,512]
    const float* b0 = (const float*)d_in[2];   // [1024]
    const float* W1 = (const float*)d_in[3];   // [1536,512]
    const float* b1 = (const float*)d_in[4];   // [1024]
    float* out = (float*)d_out;                // h [T,B,512] fp32, then c_last [B,512] fp32

    // ws layout (bytes); total ~166 MiB
    char* ws = (char*)d_ws;
    ushort_t* xb     = (ushort_t*)(ws);                          // 32 MiB
    ushort_t* h1     = (ushort_t*)(ws + 33554432);               // 32 MiB
    ushort_t* W0b    = (ushort_t*)(ws + 67108864);               // 1.5 MiB
    ushort_t* W1b    = (ushort_t*)(ws + 68681728);               // 1.5 MiB
    float*    Sa     = (float*)   (ws + 70254592);               // 1 MiB
    float*    Sb     = (float*)   (ws + 71303168);               // 1 MiB
    float*    centry = (float*)   (ws + 72351744);               // 1 MiB
    ushort_t* U      = (ushort_t*)(ws + 73400320);               // 96 MiB

    // converts
    cvt_f32_bf16<<<(M_DIM * K_DIM / 4 + 255) / 256, 256, 0, stream>>>(x, xb, M_DIM * K_DIM / 4);
    cvt_f32_bf16<<<(N3H * K_DIM / 4 + 255) / 256, 256, 0, stream>>>(W0, W0b, N3H * K_DIM / 4);
    cvt_f32_bf16<<<(N3H * K_DIM / 4 + 255) / 256, 256, 0, stream>>>(W1, W1b, N3H * K_DIM / 4);

    const int gemm_grid = (M_DIM / 128) * (N3H / 128);   // 3072
    const int scan_grid = B_DIM * NCHUNK;                 // 512

    // ---- layer 1 ----
    gemm_bt<<<gemm_grid, 256, 0, stream>>>(xb, W0b, U, M_DIM, N3H, K_DIM);
    scan_summary<<<scan_grid, 128, 0, stream>>>(U, b0, Sa, Sb);
    scan_fixup<<<NCHAIN / 256, 256, 0, stream>>>(Sa, Sb, centry, nullptr);
    scan_apply<false, true><<<scan_grid, 128, 0, stream>>>(U, b0, centry, (const void*)x, (void*)h1);

    // ---- layer 2 ----
    gemm_bt<<<gemm_grid, 256, 0, stream>>>(h1, W1b, U, M_DIM, N3H, K_DIM);
    scan_summary<<<scan_grid, 128, 0, stream>>>(U, b1, Sa, Sb);
    scan_fixup<<<NCHAIN / 256, 256, 0, stream>>>(Sa, Sb, centry, out + (size_t)M_DIM * H_DIM);
    scan_apply<true, false><<<scan_grid, 128, 0, stream>>>(U, b1, centry, (const void*)h1, (void*)out);
}

// Round 2
// 336.670 us; speedup vs baseline: 1.1471x; 1.1471x over previous
//
#include <hip/hip_runtime.h>
#include <hip/hip_bf16.h>

// SRU: T=4096 B=8 D=H=512, two layers.
// Per layer: bf16 MFMA GEMM (U = in @ W^T) -> chunked parallel linear scan -> highway epilogue.

#define T_DIM 4096
#define B_DIM 8
#define H_DIM 512
#define M_DIM (T_DIM * B_DIM)   // 32768 rows
#define N3H 1536                // 3*H
#define K_DIM 512
#define NCHUNK 256
#define CLEN (T_DIM / NCHUNK)   // 16
#define NCHAIN (B_DIM * H_DIM)  // 4096

typedef __attribute__((ext_vector_type(8))) short s16x8;   // 8 bf16 (4 VGPRs)
typedef __attribute__((ext_vector_type(4))) float f32x4;
typedef unsigned short ushort_t;
typedef unsigned int uint_t;

__device__ __forceinline__ float bf2f(ushort_t u) {
    return __uint_as_float(((uint_t)u) << 16);
}
__device__ __forceinline__ ushort_t f2bf(float f) {
    uint_t u = __float_as_uint(f);
    u += 0x7FFFu + ((u >> 16) & 1u);   // RNE
    return (ushort_t)(u >> 16);
}
__device__ __forceinline__ float sigm(float z) {
    return 1.0f / (1.0f + __expf(-z));
}
__device__ __forceinline__ float tanh_fast(float z) {
    float e = __expf(2.0f * z);
    return (e - 1.0f) / (e + 1.0f);
}

// ---------------- fp32 -> bf16 convert (vectorized) ----------------
__global__ void cvt_f32_bf16(const float* __restrict__ in, ushort_t* __restrict__ out, int n4) {
    int i = blockIdx.x * blockDim.x + threadIdx.x;
    if (i < n4) {
        float4 v = reinterpret_cast<const float4*>(in)[i];
        ushort4 o;
        o.x = f2bf(v.x); o.y = f2bf(v.y); o.z = f2bf(v.z); o.w = f2bf(v.w);
        reinterpret_cast<ushort4*>(out)[i] = o;
    }
}

// ---------------- bf16 GEMM, B-transposed input (m97 structure + XCD swizzle) ----------------
// C[M][N] = A[M][K] * B[N][K]^T, all bf16 (bits as ushort), C written bf16.
// 128x128 tile, BK=64, 256 threads (4 waves as 2x2, each wave 64x64 via 4x4 frags of 16x16x32).
__global__ void gemm_bt(const ushort_t* __restrict__ A, const ushort_t* __restrict__ Bm,
                        ushort_t* __restrict__ C, int M, int N, int K) {
    __shared__ ushort_t As[128 * 64];
    __shared__ ushort_t Bs[128 * 64];
    const int ntn = N >> 7;
    // XCD-aware swizzle: grid%8==0 -> each XCD owns a contiguous tile chunk.
    const int nwg = gridDim.x;
    const int bid = (int)blockIdx.x;
    const int id = (bid & 7) * (nwg >> 3) + (bid >> 3);
    const int tm = id / ntn;
    const int tn = id % ntn;
    const int row0 = tm << 7, col0 = tn << 7;
    const int tid = threadIdx.x;
    const int wave = tid >> 6, lane = tid & 63;
    const int frow = (wave >> 1) << 6;   // wave row offset: 0/64
    const int fcol = (wave & 1) << 6;    // wave col offset: 0/64
    f32x4 acc[4][4] = {};

    const int lr = lane >> 3;            // 0..7 row within 8-row segment
    const int lc = (lane & 7) << 3;      // element col within row (8 elems = 16B)

    for (int k0 = 0; k0 < K; k0 += 64) {
#pragma unroll
        for (int i = 0; i < 4; ++i) {
            const int r = i * 32 + wave * 8;   // wave-uniform segment base row
            const ushort_t* ga = A + (size_t)(row0 + r + lr) * K + k0 + lc;
            const ushort_t* gb = Bm + (size_t)(col0 + r + lr) * K + k0 + lc;
            __builtin_amdgcn_global_load_lds(
                (const __attribute__((address_space(1))) void*)ga,
                (__attribute__((address_space(3))) void*)&As[r * 64], 16, 0, 0);
            __builtin_amdgcn_global_load_lds(
                (const __attribute__((address_space(1))) void*)gb,
                (__attribute__((address_space(3))) void*)&Bs[r * 64], 16, 0, 0);
        }
        __syncthreads();
#pragma unroll
        for (int kk = 0; kk < 64; kk += 32) {
            const int kb = kk + ((lane >> 4) << 3);
            s16x8 af[4], bfr[4];
#pragma unroll
            for (int m = 0; m < 4; ++m)
                af[m] = *reinterpret_cast<const s16x8*>(&As[(frow + m * 16 + (lane & 15)) * 64 + kb]);
#pragma unroll
            for (int n = 0; n < 4; ++n)
                bfr[n] = *reinterpret_cast<const s16x8*>(&Bs[(fcol + n * 16 + (lane & 15)) * 64 + kb]);
#pragma unroll
            for (int m = 0; m < 4; ++m)
#pragma unroll
                for (int n = 0; n < 4; ++n)
                    acc[m][n] = __builtin_amdgcn_mfma_f32_16x16x32_bf16(af[m], bfr[n], acc[m][n], 0, 0, 0);
        }
        __syncthreads();
    }
    const int crow = (lane >> 4) << 2;
    const int ccol = lane & 15;
#pragma unroll
    for (int m = 0; m < 4; ++m)
#pragma unroll
        for (int n = 0; n < 4; ++n)
#pragma unroll
            for (int v = 0; v < 4; ++v)
                C[(size_t)(row0 + frow + m * 16 + crow + v) * N + (col0 + fcol + n * 16 + ccol)] =
                    f2bf(acc[m][n][v]);
}

// ---------------- scan pass A: per-chunk summaries (A=prod f, B=local c) ----------------
// grid: B_DIM*NCHUNK blocks, 128 threads; thread handles 4 h-values of one (b, chunk).
__global__ void scan_summary(const ushort_t* __restrict__ U, const float* __restrict__ bias,
                             float* __restrict__ Sa, float* __restrict__ Sb) {
    const int b = blockIdx.x / NCHUNK;
    const int chunk = blockIdx.x % NCHUNK;
    const int h = threadIdx.x << 2;
    float fb[4];
#pragma unroll
    for (int j = 0; j < 4; ++j) fb[j] = bias[h + j];
    float Aa[4] = {1.f, 1.f, 1.f, 1.f};
    float Bb[4] = {0.f, 0.f, 0.f, 0.f};
    const ushort_t* rp = U + ((size_t)(chunk * CLEN) * B_DIM + b) * N3H + h;
    ushort4 xt = *reinterpret_cast<const ushort4*>(rp);
    ushort4 fp = *reinterpret_cast<const ushort4*>(rp + H_DIM);
#pragma unroll
    for (int s = 0; s < CLEN; ++s) {
        ushort4 xt_n, fp_n;
        if (s + 1 < CLEN) {
            rp += (size_t)B_DIM * N3H;
            xt_n = *reinterpret_cast<const ushort4*>(rp);
            fp_n = *reinterpret_cast<const ushort4*>(rp + H_DIM);
        }
        float xs[4] = {bf2f(xt.x), bf2f(xt.y), bf2f(xt.z), bf2f(xt.w)};
        float fs[4] = {bf2f(fp.x), bf2f(fp.y), bf2f(fp.z), bf2f(fp.w)};
#pragma unroll
        for (int j = 0; j < 4; ++j) {
            float f = sigm(fs[j] + fb[j]);
            Aa[j] *= f;
            Bb[j] = f * Bb[j] + (1.f - f) * xs[j];
        }
        xt = xt_n; fp = fp_n;
    }
    const int cb = chunk * NCHAIN + b * H_DIM + h;
#pragma unroll
    for (int j = 0; j < 4; ++j) { Sa[cb + j] = Aa[j]; Sb[cb + j] = Bb[j]; }
}

// ---------------- scan pass B: combine chunk summaries per chain (in-place centry into Sa) ----------------
// NOTE: no __restrict__ on Sa — we read Sa[k]/Sb[k] then overwrite Sa[k] with the entry value.
__global__ void scan_fixup(float* Sa, const float* Sb, float* __restrict__ clast) {
    const int chain = blockIdx.x * blockDim.x + threadIdx.x;  // 4096 chains
    float c = 0.f;
    float a = Sa[chain];
    float bv = Sb[chain];
#pragma unroll 4
    for (int k = 0; k < NCHUNK; ++k) {
        float a_n = 0.f, b_n = 0.f;
        if (k + 1 < NCHUNK) {
            a_n = Sa[(k + 1) * NCHAIN + chain];
            b_n = Sb[(k + 1) * NCHAIN + chain];
        }
        Sa[k * NCHAIN + chain] = c;       // centry written in place (after next-load)
        c = a * c + bv;
        a = a_n; bv = b_n;
    }
    if (clast) clast[chain] = c;   // chain = b*H + h -> [B][H]
}

// ---------------- scan pass C: apply with correct entry c + highway epilogue ----------------
template <bool IN_BF16, bool OUT_BF16>
__global__ void scan_apply(const ushort_t* __restrict__ U, const float* __restrict__ bias,
                           const float* __restrict__ centry,
                           const void* __restrict__ xin, void* __restrict__ hout) {
    const int b = blockIdx.x / NCHUNK;
    const int chunk = blockIdx.x % NCHUNK;
    const int h = threadIdx.x << 2;
    const int cb = chunk * NCHAIN + b * H_DIM + h;
    float cc[4], fb[4], rb[4];
#pragma unroll
    for (int j = 0; j < 4; ++j) {
        cc[j] = centry[cb + j];
        fb[j] = bias[h + j];
        rb[j] = bias[H_DIM + h + j];
    }
    size_t row = (size_t)(chunk * CLEN) * B_DIM + b;
    const ushort_t* rp = U + row * N3H + h;
    size_t xoff = row * H_DIM + h;

    ushort4 xt = *reinterpret_cast<const ushort4*>(rp);
    ushort4 fp = *reinterpret_cast<const ushort4*>(rp + H_DIM);
    ushort4 rr = *reinterpret_cast<const ushort4*>(rp + 2 * H_DIM);
    float xv[4];
    if (IN_BF16) {
        ushort4 xi = *reinterpret_cast<const ushort4*>((const ushort_t*)xin + xoff);
        xv[0] = bf2f(xi.x); xv[1] = bf2f(xi.y); xv[2] = bf2f(xi.z); xv[3] = bf2f(xi.w);
    } else {
        float4 xi = *reinterpret_cast<const float4*>((const float*)xin + xoff);
        xv[0] = xi.x; xv[1] = xi.y; xv[2] = xi.z; xv[3] = xi.w;
    }

#pragma unroll
    for (int s = 0; s < CLEN; ++s) {
        // prefetch next step
        ushort4 xt_n, fp_n, rr_n;
        float xv_n[4];
        if (s + 1 < CLEN) {
            rp += (size_t)B_DIM * N3H;
            xt_n = *reinterpret_cast<const ushort4*>(rp);
            fp_n = *reinterpret_cast<const ushort4*>(rp + H_DIM);
            rr_n = *reinterpret_cast<const ushort4*>(rp + 2 * H_DIM);
            size_t xo2 = xoff + (size_t)B_DIM * H_DIM;
            if (IN_BF16) {
                ushort4 xi = *reinterpret_cast<const ushort4*>((const ushort_t*)xin + xo2);
                xv_n[0] = bf2f(xi.x); xv_n[1] = bf2f(xi.y); xv_n[2] = bf2f(xi.z); xv_n[3] = bf2f(xi.w);
            } else {
                float4 xi = *reinterpret_cast<const float4*>((const float*)xin + xo2);
                xv_n[0] = xi.x; xv_n[1] = xi.y; xv_n[2] = xi.z; xv_n[3] = xi.w;
            }
        }
        float xts[4] = {bf2f(xt.x), bf2f(xt.y), bf2f(xt.z), bf2f(xt.w)};
        float fps[4] = {bf2f(fp.x), bf2f(fp.y), bf2f(fp.z), bf2f(fp.w)};
        float rps[4] = {bf2f(rr.x), bf2f(rr.y), bf2f(rr.z), bf2f(rr.w)};
        float hv[4];
#pragma unroll
        for (int j = 0; j < 4; ++j) {
            float f = sigm(fps[j] + fb[j]);
            cc[j] = f * cc[j] + (1.f - f) * xts[j];
            float r = sigm(rps[j] + rb[j]);
            hv[j] = r * tanh_fast(cc[j]) + (1.f - r) * xv[j];
        }
        if (OUT_BF16) {
            ushort4 o;
            o.x = f2bf(hv[0]); o.y = f2bf(hv[1]); o.z = f2bf(hv[2]); o.w = f2bf(hv[3]);
            *reinterpret_cast<ushort4*>((ushort_t*)hout + xoff) = o;
        } else {
            float4 o;
            o.x = hv[0]; o.y = hv[1]; o.z = hv[2]; o.w = hv[3];
            *reinterpret_cast<float4*>((float*)hout + xoff) = o;
        }
        xoff += (size_t)B_DIM * H_DIM;
        xt = xt_n; fp = fp_n; rr = rr_n;
        xv[0] = xv_n[0]; xv[1] = xv_n[1]; xv[2] = xv_n[2]; xv[3] = xv_n[3];
    }
}

extern "C" void kernel_launch(void* const* d_in, const int* in_sizes, int n_in,
                              void* d_out, int out_size, void* d_ws, size_t ws_size,
                              hipStream_t stream) {
    (void)in_sizes; (void)n_in; (void)out_size; (void)ws_size;
    const float* x  = (const float*)d_in[0];   // [T,B,512]
    const float* W0 = (const float*)d_in[1];   // [1536,512]
    const float* b0 = (const float*)d_in[2];   // [1024]
    const float* W1 = (const float*)d_in[3];   // [1536,512]
    const float* b1 = (const float*)d_in[4];   // [1024]
    float* out = (float*)d_out;                // h [T,B,512] fp32, then c_last [B,512] fp32

    // ws layout (bytes); total 163 MiB (round-1 proved >=166 MiB available)
    // [0,32M):   xb (bf16 x) -- dead after GEMM1; Sa/Sb alias here afterwards
    // [32,64M):  h1 (bf16)
    // [64,65.5M): W0b   [65.5,67M): W1b
    // [67,163M): U (bf16, 96 MiB)
    char* ws = (char*)d_ws;
    ushort_t* xb  = (ushort_t*)(ws);
    float*    Sa  = (float*)(ws);                 // 4 MiB (aliases xb after GEMM1)
    float*    Sb  = (float*)(ws + 4194304);       // 4 MiB
    ushort_t* h1  = (ushort_t*)(ws + 33554432);   // 32 MiB
    ushort_t* W0b = (ushort_t*)(ws + 67108864);   // 1.5 MiB
    ushort_t* W1b = (ushort_t*)(ws + 68681728);   // 1.5 MiB
    ushort_t* U   = (ushort_t*)(ws + 70254592);   // 96 MiB

    // converts
    cvt_f32_bf16<<<(M_DIM * K_DIM / 4 + 255) / 256, 256, 0, stream>>>(x, xb, M_DIM * K_DIM / 4);
    cvt_f32_bf16<<<(N3H * K_DIM / 4 + 255) / 256, 256, 0, stream>>>(W0, W0b, N3H * K_DIM / 4);
    cvt_f32_bf16<<<(N3H * K_DIM / 4 + 255) / 256, 256, 0, stream>>>(W1, W1b, N3H * K_DIM / 4);

    const int gemm_grid = (M_DIM / 128) * (N3H / 128);   // 3072 (%8==0 for XCD swizzle)
    const int scan_grid = B_DIM * NCHUNK;                 // 2048

    // ---- layer 1 ----
    gemm_bt<<<gemm_grid, 256, 0, stream>>>(xb, W0b, U, M_DIM, N3H, K_DIM);
    // xb dead from here; Sa/Sb occupy its space
    scan_summary<<<scan_grid, 128, 0, stream>>>(U, b0, Sa, Sb);
    scan_fixup<<<NCHAIN / 256, 256, 0, stream>>>(Sa, Sb, nullptr);
    scan_apply<false, true><<<scan_grid, 128, 0, stream>>>(U, b0, Sa, (const void*)x, (void*)h1);

    // ---- layer 2 ----
    gemm_bt<<<gemm_grid, 256, 0, stream>>>(h1, W1b, U, M_DIM, N3H, K_DIM);
    scan_summary<<<scan_grid, 128, 0, stream>>>(U, b1, Sa, Sb);
    scan_fixup<<<NCHAIN / 256, 256, 0, stream>>>(Sa, Sb, out + (size_t)M_DIM * H_DIM);
    scan_apply<true, false><<<scan_grid, 128, 0, stream>>>(U, b1, Sa, (const void*)h1, (void*)out);
}

// Round 3
// 288.740 us; speedup vs baseline: 1.3375x; 1.1660x over previous
//
#include <hip/hip_runtime.h>
#include <hip/hip_bf16.h>

// SRU: T=4096 B=8 D=H=512, two layers.
// Per layer: bf16 MFMA GEMM 256^2/8-wave phase-split (U = in @ W^T) -> chunked parallel linear scan -> highway.

#define T_DIM 4096
#define B_DIM 8
#define H_DIM 512
#define M_DIM (T_DIM * B_DIM)   // 32768 rows
#define N3H 1536                // 3*H
#define K_DIM 512
#define NCHUNK 256
#define CLEN (T_DIM / NCHUNK)   // 16
#define NCHAIN (B_DIM * H_DIM)  // 4096
#define NGRP 16
#define GLEN (NCHUNK / NGRP)    // 16

typedef __attribute__((ext_vector_type(8))) short s16x8;   // 8 bf16 (4 VGPRs)
typedef __attribute__((ext_vector_type(4))) float f32x4;
typedef unsigned short ushort_t;
typedef unsigned int uint_t;

__device__ __forceinline__ float bf2f(ushort_t u) {
    return __uint_as_float(((uint_t)u) << 16);
}
__device__ __forceinline__ ushort_t f2bf(float f) {
    uint_t u = __float_as_uint(f);
    u += 0x7FFFu + ((u >> 16) & 1u);   // RNE
    return (ushort_t)(u >> 16);
}
__device__ __forceinline__ float sigm(float z) {
    return 1.0f / (1.0f + __expf(-z));
}
__device__ __forceinline__ float tanh_fast(float z) {
    float e = __expf(2.0f * z);
    return (e - 1.0f) / (e + 1.0f);
}

// ---------------- fused fp32 -> bf16 convert for x, W0, W1 ----------------
#define XF4 (M_DIM * K_DIM / 4)          // 4194304 float4
#define WF4 (N3H * K_DIM / 4)            // 196608 float4
__global__ void cvt_all(const float* __restrict__ x, const float* __restrict__ w0,
                        const float* __restrict__ w1, ushort_t* __restrict__ xb,
                        ushort_t* __restrict__ w0b, ushort_t* __restrict__ w1b) {
    int i = blockIdx.x * blockDim.x + threadIdx.x;
    const float* src; ushort_t* dst; int idx;
    if (i < XF4) { src = x; dst = xb; idx = i; }
    else if (i < XF4 + WF4) { src = w0; dst = w0b; idx = i - XF4; }
    else if (i < XF4 + 2 * WF4) { src = w1; dst = w1b; idx = i - XF4 - WF4; }
    else return;
    float4 v = reinterpret_cast<const float4*>(src)[idx];
    ushort4 o;
    o.x = f2bf(v.x); o.y = f2bf(v.y); o.z = f2bf(v.z); o.w = f2bf(v.w);
    reinterpret_cast<ushort4*>(dst)[idx] = o;
}

// ---------------- bf16 GEMM 256x256 tile, BK=64, 8 waves (2Mx4N), phase-split ----------------
// C[M][N] = A[M][K] * B[N][K]^T (both row-major, K contiguous), C written bf16.
// LDS: 2 dbuf x (A 256x64 + B 256x64) bf16 = 128 KiB. XOR-swizzle byte^=((row&7)<<4),
// applied on BOTH sides: pre-swizzled global source for global_load_lds (linear LDS dest)
// + swizzled ds_read address (rule 21 / m201 pattern).
__device__ __forceinline__ s16x8 lds_swz_read(const ushort_t* base, int row, int kb) {
    int byte = (row << 7) + (((kb << 1)) ^ ((row & 7) << 4));
    return *reinterpret_cast<const s16x8*>(reinterpret_cast<const char*>(base) + byte);
}

__global__ __launch_bounds__(512) void gemm_bt256(const ushort_t* __restrict__ A,
                                                  const ushort_t* __restrict__ Bm,
                                                  ushort_t* __restrict__ C,
                                                  int M, int N, int K) {
    __shared__ ushort_t As[2][256 * 64];
    __shared__ ushort_t Bs[2][256 * 64];
    const int ntn = N >> 8;                      // 6 col tiles
    const int nwg = gridDim.x;                   // 768 (%8==0)
    const int bid = (int)blockIdx.x;
    const int id = (bid & 7) * (nwg >> 3) + (bid >> 3);   // XCD swizzle (bijective)
    const int tm = id / ntn, tn = id % ntn;
    const int row0 = tm << 8, col0 = tn << 8;
    const int tid = threadIdx.x;
    const int wv = tid >> 6, lane = tid & 63;
    const int wm = wv >> 2, wn = wv & 3;         // 2M x 4N waves; wave tile 128x64
    const int l15 = lane & 15;
    const int kgrp = (lane >> 4) << 3;           // 0,8,16,24

    f32x4 acc[8][4] = {};                        // 8 m-frags x 4 n-frags of 16x16

    // staging: per tile, 4 rounds of (A,B); each wave covers 8 rows/round; lane->row(lane>>3), slot(lane&7)
    const int srow_in_wave = lane >> 3;
    const int sslot = lane & 7;

#define STAGE(buf_, t_)                                                                  \
    {                                                                                    \
        const int k0s = (t_) * 64;                                                       \
        _Pragma("unroll")                                                                \
        for (int j = 0; j < 4; ++j) {                                                    \
            const int rl = j * 64 + wv * 8;                                              \
            const int rme = rl + srow_in_wave;                                           \
            const int sl = sslot ^ (rme & 7);   /* inverse swizzle on source */          \
            const ushort_t* ga = A + (size_t)(row0 + rme) * K + k0s + (sl << 3);         \
            const ushort_t* gb = Bm + (size_t)(col0 + rme) * K + k0s + (sl << 3);        \
            __builtin_amdgcn_global_load_lds(                                            \
                (const __attribute__((address_space(1))) void*)ga,                       \
                (__attribute__((address_space(3))) void*)&As[buf_][rl * 64], 16, 0, 0);  \
            __builtin_amdgcn_global_load_lds(                                            \
                (const __attribute__((address_space(1))) void*)gb,                       \
                (__attribute__((address_space(3))) void*)&Bs[buf_][rl * 64], 16, 0, 0);  \
        }                                                                                \
    }

    // prologue: stage tile 0, wait, barrier
    STAGE(0, 0);
    asm volatile("s_waitcnt vmcnt(0)" ::: "memory");
    __builtin_amdgcn_s_barrier();

    const int nkt = K >> 6;                      // 8
    for (int t = 0; t < nkt; ++t) {
        const int buf = t & 1;
        const ushort_t* Ab = &As[buf][0];
        const ushort_t* Bb = &Bs[buf][0];
        if (t + 1 < nkt) STAGE(buf ^ 1, t + 1);  // issue next-tile loads early (race-free: other buffer)

        s16x8 af[4][2], bfr[4][2];
        // ---- phase 0: mh=0, nh=0 : read A-half0 (8) + B n0,n1 (4) ----
#pragma unroll
        for (int j = 0; j < 4; ++j)
#pragma unroll
            for (int kk2 = 0; kk2 < 2; ++kk2)
                af[j][kk2] = lds_swz_read(Ab, wm * 128 + j * 16 + l15, kk2 * 32 + kgrp);
#pragma unroll
        for (int n = 0; n < 2; ++n)
#pragma unroll
            for (int kk2 = 0; kk2 < 2; ++kk2)
                bfr[n][kk2] = lds_swz_read(Bb, wn * 64 + n * 16 + l15, kk2 * 32 + kgrp);
        __builtin_amdgcn_s_barrier();
        __builtin_amdgcn_s_setprio(1);
#pragma unroll
        for (int j = 0; j < 4; ++j)
#pragma unroll
            for (int n = 0; n < 2; ++n)
#pragma unroll
                for (int kk2 = 0; kk2 < 2; ++kk2)
                    acc[j][n] = __builtin_amdgcn_mfma_f32_16x16x32_bf16(af[j][kk2], bfr[n][kk2], acc[j][n], 0, 0, 0);
        __builtin_amdgcn_s_setprio(0);
        __builtin_amdgcn_s_barrier();

        // ---- phase 1: mh=0, nh=1 : read B n2,n3 (4) ----
#pragma unroll
        for (int n = 2; n < 4; ++n)
#pragma unroll
            for (int kk2 = 0; kk2 < 2; ++kk2)
                bfr[n][kk2] = lds_swz_read(Bb, wn * 64 + n * 16 + l15, kk2 * 32 + kgrp);
        __builtin_amdgcn_s_barrier();
        __builtin_amdgcn_s_setprio(1);
#pragma unroll
        for (int j = 0; j < 4; ++j)
#pragma unroll
            for (int n = 2; n < 4; ++n)
#pragma unroll
                for (int kk2 = 0; kk2 < 2; ++kk2)
                    acc[j][n] = __builtin_amdgcn_mfma_f32_16x16x32_bf16(af[j][kk2], bfr[n][kk2], acc[j][n], 0, 0, 0);
        __builtin_amdgcn_s_setprio(0);
        __builtin_amdgcn_s_barrier();

        // ---- phase 2: mh=1, nh=0 : read A-half1 (8) ----
#pragma unroll
        for (int j = 0; j < 4; ++j)
#pragma unroll
            for (int kk2 = 0; kk2 < 2; ++kk2)
                af[j][kk2] = lds_swz_read(Ab, wm * 128 + (4 + j) * 16 + l15, kk2 * 32 + kgrp);
        __builtin_amdgcn_s_barrier();
        __builtin_amdgcn_s_setprio(1);
#pragma unroll
        for (int j = 0; j < 4; ++j)
#pragma unroll
            for (int n = 0; n < 2; ++n)
#pragma unroll
                for (int kk2 = 0; kk2 < 2; ++kk2)
                    acc[4 + j][n] = __builtin_amdgcn_mfma_f32_16x16x32_bf16(af[j][kk2], bfr[n][kk2], acc[4 + j][n], 0, 0, 0);
        __builtin_amdgcn_s_setprio(0);
        __builtin_amdgcn_s_barrier();

        // ---- phase 3: mh=1, nh=1 : no reads ----
        __builtin_amdgcn_s_setprio(1);
#pragma unroll
        for (int j = 0; j < 4; ++j)
#pragma unroll
            for (int n = 2; n < 4; ++n)
#pragma unroll
                for (int kk2 = 0; kk2 < 2; ++kk2)
                    acc[4 + j][n] = __builtin_amdgcn_mfma_f32_16x16x32_bf16(af[j][kk2], bfr[n][kk2], acc[4 + j][n], 0, 0, 0);
        __builtin_amdgcn_s_setprio(0);

        // iteration end: ensure next tile fully landed (loads issued ~4 phases ago) for all waves
        asm volatile("s_waitcnt vmcnt(0)" ::: "memory");
        __builtin_amdgcn_s_barrier();
    }
#undef STAGE

    // epilogue: C/D layout col=lane&15, row=(lane>>4)*4+v (m89-verified; same as round-2 kernel)
    const int crow = (lane >> 4) << 2;
#pragma unroll
    for (int m = 0; m < 8; ++m)
#pragma unroll
        for (int n = 0; n < 4; ++n)
#pragma unroll
            for (int v = 0; v < 4; ++v)
                C[(size_t)(row0 + wm * 128 + m * 16 + crow + v) * N + (col0 + wn * 64 + n * 16 + l15)] =
                    f2bf(acc[m][n][v]);
}

// ---------------- scan pass A: per-chunk summaries (A=prod f, B=local c) ----------------
__global__ void scan_summary(const ushort_t* __restrict__ U, const float* __restrict__ bias,
                             float* __restrict__ Sa, float* __restrict__ Sb) {
    const int b = blockIdx.x / NCHUNK;
    const int chunk = blockIdx.x % NCHUNK;
    const int h = threadIdx.x << 2;
    float fb[4];
#pragma unroll
    for (int j = 0; j < 4; ++j) fb[j] = bias[h + j];
    float Aa[4] = {1.f, 1.f, 1.f, 1.f};
    float Bb[4] = {0.f, 0.f, 0.f, 0.f};
    const ushort_t* rp = U + ((size_t)(chunk * CLEN) * B_DIM + b) * N3H + h;
    ushort4 xt = *reinterpret_cast<const ushort4*>(rp);
    ushort4 fp = *reinterpret_cast<const ushort4*>(rp + H_DIM);
#pragma unroll
    for (int s = 0; s < CLEN; ++s) {
        ushort4 xt_n, fp_n;
        if (s + 1 < CLEN) {
            rp += (size_t)B_DIM * N3H;
            xt_n = *reinterpret_cast<const ushort4*>(rp);
            fp_n = *reinterpret_cast<const ushort4*>(rp + H_DIM);
        }
        float xs[4] = {bf2f(xt.x), bf2f(xt.y), bf2f(xt.z), bf2f(xt.w)};
        float fs[4] = {bf2f(fp.x), bf2f(fp.y), bf2f(fp.z), bf2f(fp.w)};
#pragma unroll
        for (int j = 0; j < 4; ++j) {
            float f = sigm(fs[j] + fb[j]);
            Aa[j] *= f;
            Bb[j] = f * Bb[j] + (1.f - f) * xs[j];
        }
        xt = xt_n; fp = fp_n;
    }
    const int cb = chunk * NCHAIN + b * H_DIM + h;
#pragma unroll
    for (int j = 0; j < 4; ++j) { Sa[cb + j] = Aa[j]; Sb[cb + j] = Bb[j]; }
}

// ---------------- scan pass B1: per-group local exclusive prefixes (in-place) + group summaries ----------------
// thread = (group g, chain); converts Sa/Sb[k] from chunk summaries to exclusive local prefixes
// (c_entry(k) = la*C_groupstart + lb), writes inclusive group summary to Ga/Gb.
__global__ void scan_fixup1(float* Sa, float* Sb, float* __restrict__ Ga, float* __restrict__ Gb) {
    const int idx = blockIdx.x * blockDim.x + threadIdx.x;   // 16*4096
    const int chain = idx & (NCHAIN - 1);
    const int g = idx >> 12;
    float A = 1.f, B = 0.f;
#pragma unroll
    for (int i = 0; i < GLEN; ++i) {
        const size_t off = (size_t)(g * GLEN + i) * NCHAIN + chain;
        float a = Sa[off], b = Sb[off];
        Sa[off] = A; Sb[off] = B;       // exclusive prefix (read-before-write, thread-owned)
        B = a * B + b;
        A = a * A;
    }
    Ga[g * NCHAIN + chain] = A;
    Gb[g * NCHAIN + chain] = B;
}

// ---------------- scan pass B2: scan group summaries -> group-entry states ----------------
__global__ void scan_fixup2(const float* __restrict__ Ga, const float* __restrict__ Gb,
                            float* __restrict__ Eg, float* __restrict__ clast) {
    const int chain = blockIdx.x * blockDim.x + threadIdx.x;  // 4096
    float c = 0.f;
#pragma unroll
    for (int g = 0; g < NGRP; ++g) {
        Eg[g * NCHAIN + chain] = c;
        c = Ga[g * NCHAIN + chain] * c + Gb[g * NCHAIN + chain];
    }
    if (clast) clast[chain] = c;   // chain = b*H + h -> [B][H]
}

// ---------------- scan pass C: apply with reconstructed entry c + highway epilogue ----------------
template <bool IN_BF16, bool OUT_BF16>
__global__ void scan_apply(const ushort_t* __restrict__ U, const float* __restrict__ bias,
                           const float* __restrict__ Sa, const float* __restrict__ Sb,
                           const float* __restrict__ Eg,
                           const void* __restrict__ xin, void* __restrict__ hout) {
    const int b = blockIdx.x / NCHUNK;
    const int chunk = blockIdx.x % NCHUNK;
    const int h = threadIdx.x << 2;
    const int cb = chunk * NCHAIN + b * H_DIM + h;
    const int eb = (chunk >> 4) * NCHAIN + b * H_DIM + h;   // group of this chunk
    float cc[4], fb[4], rb[4];
    float4 la = *reinterpret_cast<const float4*>(&Sa[cb]);
    float4 lb = *reinterpret_cast<const float4*>(&Sb[cb]);
    float4 eg = *reinterpret_cast<const float4*>(&Eg[eb]);
    cc[0] = lb.x + la.x * eg.x; cc[1] = lb.y + la.y * eg.y;
    cc[2] = lb.z + la.z * eg.z; cc[3] = lb.w + la.w * eg.w;
#pragma unroll
    for (int j = 0; j < 4; ++j) {
        fb[j] = bias[h + j];
        rb[j] = bias[H_DIM + h + j];
    }
    size_t row = (size_t)(chunk * CLEN) * B_DIM + b;
    const ushort_t* rp = U + row * N3H + h;
    size_t xoff = row * H_DIM + h;

    ushort4 xt = *reinterpret_cast<const ushort4*>(rp);
    ushort4 fp = *reinterpret_cast<const ushort4*>(rp + H_DIM);
    ushort4 rr = *reinterpret_cast<const ushort4*>(rp + 2 * H_DIM);
    float xv[4];
    if (IN_BF16) {
        ushort4 xi = *reinterpret_cast<const ushort4*>((const ushort_t*)xin + xoff);
        xv[0] = bf2f(xi.x); xv[1] = bf2f(xi.y); xv[2] = bf2f(xi.z); xv[3] = bf2f(xi.w);
    } else {
        float4 xi = *reinterpret_cast<const float4*>((const float*)xin + xoff);
        xv[0] = xi.x; xv[1] = xi.y; xv[2] = xi.z; xv[3] = xi.w;
    }

#pragma unroll
    for (int s = 0; s < CLEN; ++s) {
        ushort4 xt_n, fp_n, rr_n;
        float xv_n[4];
        if (s + 1 < CLEN) {
            rp += (size_t)B_DIM * N3H;
            xt_n = *reinterpret_cast<const ushort4*>(rp);
            fp_n = *reinterpret_cast<const ushort4*>(rp + H_DIM);
            rr_n = *reinterpret_cast<const ushort4*>(rp + 2 * H_DIM);
            size_t xo2 = xoff + (size_t)B_DIM * H_DIM;
            if (IN_BF16) {
                ushort4 xi = *reinterpret_cast<const ushort4*>((const ushort_t*)xin + xo2);
                xv_n[0] = bf2f(xi.x); xv_n[1] = bf2f(xi.y); xv_n[2] = bf2f(xi.z); xv_n[3] = bf2f(xi.w);
            } else {
                float4 xi = *reinterpret_cast<const float4*>((const float*)xin + xo2);
                xv_n[0] = xi.x; xv_n[1] = xi.y; xv_n[2] = xi.z; xv_n[3] = xi.w;
            }
        }
        float xts[4] = {bf2f(xt.x), bf2f(xt.y), bf2f(xt.z), bf2f(xt.w)};
        float fps[4] = {bf2f(fp.x), bf2f(fp.y), bf2f(fp.z), bf2f(fp.w)};
        float rps[4] = {bf2f(rr.x), bf2f(rr.y), bf2f(rr.z), bf2f(rr.w)};
        float hv[4];
#pragma unroll
        for (int j = 0; j < 4; ++j) {
            float f = sigm(fps[j] + fb[j]);
            cc[j] = f * cc[j] + (1.f - f) * xts[j];
            float r = sigm(rps[j] + rb[j]);
            hv[j] = r * tanh_fast(cc[j]) + (1.f - r) * xv[j];
        }
        if (OUT_BF16) {
            ushort4 o;
            o.x = f2bf(hv[0]); o.y = f2bf(hv[1]); o.z = f2bf(hv[2]); o.w = f2bf(hv[3]);
            *reinterpret_cast<ushort4*>((ushort_t*)hout + xoff) = o;
        } else {
            float4 o;
            o.x = hv[0]; o.y = hv[1]; o.z = hv[2]; o.w = hv[3];
            *reinterpret_cast<float4*>((float*)hout + xoff) = o;
        }
        xoff += (size_t)B_DIM * H_DIM;
        xt = xt_n; fp = fp_n; rr = rr_n;
        xv[0] = xv_n[0]; xv[1] = xv_n[1]; xv[2] = xv_n[2]; xv[3] = xv_n[3];
    }
}

extern "C" void kernel_launch(void* const* d_in, const int* in_sizes, int n_in,
                              void* d_out, int out_size, void* d_ws, size_t ws_size,
                              hipStream_t stream) {
    (void)in_sizes; (void)n_in; (void)out_size; (void)ws_size;
    const float* x  = (const float*)d_in[0];   // [T,B,512]
    const float* W0 = (const float*)d_in[1];   // [1536,512]
    const float* b0 = (const float*)d_in[2];   // [1024]
    const float* W1 = (const float*)d_in[3];   // [1536,512]
    const float* b1 = (const float*)d_in[4];   // [1024]
    float* out = (float*)d_out;                // h [T,B,512] fp32, then c_last [B,512] fp32

    // ws layout (bytes); total 163 MiB.
    // [0,32M): xb (bf16 x) -- dead after GEMM1; Sa/Sb/Ga/Gb/Eg alias here afterwards
    char* ws = (char*)d_ws;
    ushort_t* xb  = (ushort_t*)(ws);
    float*    Sa  = (float*)(ws);                 // 4 MiB
    float*    Sb  = (float*)(ws + 4194304);       // 4 MiB
    float*    Ga  = (float*)(ws + 8388608);       // 256 KiB
    float*    Gb  = (float*)(ws + 8650752);       // 256 KiB
    float*    Eg  = (float*)(ws + 8912896);       // 256 KiB
    ushort_t* h1  = (ushort_t*)(ws + 33554432);   // 32 MiB
    ushort_t* W0b = (ushort_t*)(ws + 67108864);   // 1.5 MiB
    ushort_t* W1b = (ushort_t*)(ws + 68681728);   // 1.5 MiB
    ushort_t* U   = (ushort_t*)(ws + 70254592);   // 96 MiB

    const int cvt_total = XF4 + 2 * WF4;
    cvt_all<<<(cvt_total + 255) / 256, 256, 0, stream>>>(x, W0, W1, xb, W0b, W1b);

    const int gemm_grid = (M_DIM / 256) * (N3H / 256);   // 768 (%8==0)
    const int scan_grid = B_DIM * NCHUNK;                 // 2048

    // ---- layer 1 ----
    gemm_bt256<<<gemm_grid, 512, 0, stream>>>(xb, W0b, U, M_DIM, N3H, K_DIM);
    scan_summary<<<scan_grid, 128, 0, stream>>>(U, b0, Sa, Sb);
    scan_fixup1<<<NGRP * NCHAIN / 256, 256, 0, stream>>>(Sa, Sb, Ga, Gb);
    scan_fixup2<<<NCHAIN / 256, 256, 0, stream>>>(Ga, Gb, Eg, nullptr);
    scan_apply<false, true><<<scan_grid, 128, 0, stream>>>(U, b0, Sa, Sb, Eg, (const void*)x, (void*)h1);

    // ---- layer 2 ----
    gemm_bt256<<<gemm_grid, 512, 0, stream>>>(h1, W1b, U, M_DIM, N3H, K_DIM);
    scan_summary<<<scan_grid, 128, 0, stream>>>(U, b1, Sa, Sb);
    scan_fixup1<<<NGRP * NCHAIN / 256, 256, 0, stream>>>(Sa, Sb, Ga, Gb);
    scan_fixup2<<<NCHAIN / 256, 256, 0, stream>>>(Ga, Gb, Eg, out + (size_t)M_DIM * H_DIM);
    scan_apply<true, false><<<scan_grid, 128, 0, stream>>>(U, b1, Sa, Sb, Eg, (const void*)h1, (void*)out);
}

// Round 4
// 285.315 us; speedup vs baseline: 1.3536x; 1.0120x over previous
//
#include <hip/hip_runtime.h>
#include <hip/hip_bf16.h>

// SRU: T=4096 B=8 D=H=512, two layers.
// Per layer: bf16 MFMA GEMM 256^2 8-wave, depth-2 counted-vmcnt pipeline (U = in @ W^T)
// -> chunked parallel linear scan -> highway epilogue.

#define T_DIM 4096
#define B_DIM 8
#define H_DIM 512
#define M_DIM (T_DIM * B_DIM)   // 32768 rows
#define N3H 1536                // 3*H
#define K_DIM 512
#define NCHUNK 512
#define CLEN (T_DIM / NCHUNK)   // 8
#define NCHAIN (B_DIM * H_DIM)  // 4096
#define NGRP 32
#define GLEN (NCHUNK / NGRP)    // 16

typedef __attribute__((ext_vector_type(8))) short s16x8;   // 8 bf16 (4 VGPRs)
typedef __attribute__((ext_vector_type(4))) float f32x4;
typedef unsigned short ushort_t;
typedef unsigned int uint_t;

__device__ __forceinline__ float bf2f(ushort_t u) {
    return __uint_as_float(((uint_t)u) << 16);
}
__device__ __forceinline__ ushort_t f2bf(float f) {
    uint_t u = __float_as_uint(f);
    u += 0x7FFFu + ((u >> 16) & 1u);   // RNE
    return (ushort_t)(u >> 16);
}
__device__ __forceinline__ float sigm(float z) {
    return 1.0f / (1.0f + __expf(-z));
}
__device__ __forceinline__ float tanh_fast(float z) {
    float e = __expf(2.0f * z);
    return (e - 1.0f) / (e + 1.0f);
}

// ---------------- fused fp32 -> bf16 convert for x, W0, W1 ----------------
#define XF4 (M_DIM * K_DIM / 4)          // 4194304 float4
#define WF4 (N3H * K_DIM / 4)            // 196608 float4
__global__ void cvt_all(const float* __restrict__ x, const float* __restrict__ w0,
                        const float* __restrict__ w1, ushort_t* __restrict__ xb,
                        ushort_t* __restrict__ w0b, ushort_t* __restrict__ w1b) {
    int i = blockIdx.x * blockDim.x + threadIdx.x;
    const float* src; ushort_t* dst; int idx;
    if (i < XF4) { src = x; dst = xb; idx = i; }
    else if (i < XF4 + WF4) { src = w0; dst = w0b; idx = i - XF4; }
    else if (i < XF4 + 2 * WF4) { src = w1; dst = w1b; idx = i - XF4 - WF4; }
    else return;
    float4 v = reinterpret_cast<const float4*>(src)[idx];
    ushort4 o;
    o.x = f2bf(v.x); o.y = f2bf(v.y); o.z = f2bf(v.z); o.w = f2bf(v.w);
    reinterpret_cast<ushort4*>(dst)[idx] = o;
}

// ---------------- bf16 GEMM 256x256 tile, BK=64, 8 waves (2Mx4N) ----------------
// C[M][N] = A[M][K] * B[N][K]^T (row-major, K contiguous), C written bf16.
// LDS: 2 dbuf x (A 256x64 + B 256x64) bf16 = 128 KiB. XOR-swizzle byte^=((row&7)<<4)
// both-sides (pre-swizzled global source + swizzled ds_read). Depth-2 tile pipeline:
// stage t+2 after compute(t), counted s_waitcnt vmcnt(8) (never 0 mid-loop).
__device__ __forceinline__ s16x8 lds_swz_read(const ushort_t* base, int row, int kb) {
    int byte = (row << 7) + (((kb << 1)) ^ ((row & 7) << 4));
    return *reinterpret_cast<const s16x8*>(reinterpret_cast<const char*>(base) + byte);
}

__global__ __launch_bounds__(512) void gemm_bt256(const ushort_t* __restrict__ A,
                                                  const ushort_t* __restrict__ Bm,
                                                  ushort_t* __restrict__ C,
                                                  int M, int N, int K) {
    __shared__ ushort_t As[2][256 * 64];
    __shared__ ushort_t Bs[2][256 * 64];
    const int ntn = N >> 8;                      // 6 col tiles
    const int nwg = gridDim.x;                   // 768 (%8==0)
    const int bid = (int)blockIdx.x;
    const int id = (bid & 7) * (nwg >> 3) + (bid >> 3);   // XCD swizzle (bijective)
    const int tm = id / ntn, tn = id % ntn;
    const int row0 = tm << 8, col0 = tn << 8;
    const int tid = threadIdx.x;
    const int wv = tid >> 6, lane = tid & 63;
    const int wm = wv >> 2, wn = wv & 3;         // 2M x 4N waves; wave tile 128x64
    const int l15 = lane & 15;
    const int kgrp = (lane >> 4) << 3;           // 0,8,16,24

    f32x4 acc[8][4] = {};                        // 8 m-frags x 4 n-frags of 16x16

    const int srow_in_wave = lane >> 3;
    const int sslot = lane & 7;

#define STAGE(buf_, t_)                                                                  \
    {                                                                                    \
        const int k0s = (t_) * 64;                                                       \
        _Pragma("unroll")                                                                \
        for (int j = 0; j < 4; ++j) {                                                    \
            const int rl = j * 64 + wv * 8;                                              \
            const int rme = rl + srow_in_wave;                                           \
            const int sl = sslot ^ (rme & 7);   /* inverse swizzle on source */          \
            const ushort_t* ga = A + (size_t)(row0 + rme) * K + k0s + (sl << 3);         \
            const ushort_t* gb = Bm + (size_t)(col0 + rme) * K + k0s + (sl << 3);        \
            __builtin_amdgcn_global_load_lds(                                            \
                (const __attribute__((address_space(1))) void*)ga,                       \
                (__attribute__((address_space(3))) void*)&As[buf_][rl * 64], 16, 0, 0);  \
            __builtin_amdgcn_global_load_lds(                                            \
                (const __attribute__((address_space(1))) void*)gb,                       \
                (__attribute__((address_space(3))) void*)&Bs[buf_][rl * 64], 16, 0, 0);  \
        }                                                                                \
    }

    // prologue: stage tiles 0 and 1 (depth-2), counted wait for tile 0 only
    STAGE(0, 0);
    STAGE(1, 1);
    asm volatile("s_waitcnt vmcnt(8)" ::: "memory");
    __builtin_amdgcn_s_barrier();

    const int nkt = K >> 6;                      // 8
    for (int t = 0; t < nkt; ++t) {
        const int buf = t & 1;
        const ushort_t* Ab = &As[buf][0];
        const ushort_t* Bb = &Bs[buf][0];

        // ---- compute full K-tile: 24 ds_read_b128 + 64 MFMA, compiler-scheduled ----
        __builtin_amdgcn_s_setprio(1);
        {
            s16x8 af[4][2], bfr[4][2];
#pragma unroll
            for (int j = 0; j < 4; ++j)
#pragma unroll
                for (int kk2 = 0; kk2 < 2; ++kk2)
                    af[j][kk2] = lds_swz_read(Ab, wm * 128 + j * 16 + l15, kk2 * 32 + kgrp);
#pragma unroll
            for (int n = 0; n < 4; ++n)
#pragma unroll
                for (int kk2 = 0; kk2 < 2; ++kk2)
                    bfr[n][kk2] = lds_swz_read(Bb, wn * 64 + n * 16 + l15, kk2 * 32 + kgrp);
#pragma unroll
            for (int j = 0; j < 4; ++j)
#pragma unroll
                for (int n = 0; n < 4; ++n)
#pragma unroll
                    for (int kk2 = 0; kk2 < 2; ++kk2)
                        acc[j][n] = __builtin_amdgcn_mfma_f32_16x16x32_bf16(af[j][kk2], bfr[n][kk2], acc[j][n], 0, 0, 0);
            // second m-half: reload A frags (rows +64), keep B frags live
#pragma unroll
            for (int j = 0; j < 4; ++j)
#pragma unroll
                for (int kk2 = 0; kk2 < 2; ++kk2)
                    af[j][kk2] = lds_swz_read(Ab, wm * 128 + (4 + j) * 16 + l15, kk2 * 32 + kgrp);
#pragma unroll
            for (int j = 0; j < 4; ++j)
#pragma unroll
                for (int n = 0; n < 4; ++n)
#pragma unroll
                    for (int kk2 = 0; kk2 < 2; ++kk2)
                        acc[4 + j][n] = __builtin_amdgcn_mfma_f32_16x16x32_bf16(af[j][kk2], bfr[n][kk2], acc[4 + j][n], 0, 0, 0);
        }
        __builtin_amdgcn_s_setprio(0);
        __builtin_amdgcn_s_barrier();            // all waves done reading buf

        if (t + 2 < nkt) STAGE(buf, t + 2);      // overwrite just-freed buffer
        if (t + 1 < nkt) {
            if (t + 2 < nkt) asm volatile("s_waitcnt vmcnt(8)" ::: "memory");  // t+1 landed, t+2 in flight
            else             asm volatile("s_waitcnt vmcnt(0)" ::: "memory");  // final drain
            __builtin_amdgcn_s_barrier();
        }
    }
#undef STAGE

    // epilogue: C/D layout col=lane&15, row=(lane>>4)*4+v (m89-verified)
    const int crow = (lane >> 4) << 2;
#pragma unroll
    for (int m = 0; m < 8; ++m)
#pragma unroll
        for (int n = 0; n < 4; ++n)
#pragma unroll
            for (int v = 0; v < 4; ++v)
                C[(size_t)(row0 + wm * 128 + m * 16 + crow + v) * N + (col0 + wn * 64 + n * 16 + l15)] =
                    f2bf(acc[m][n][v]);
}

// ---------------- scan pass A: per-chunk summaries (A=prod f, B=local c) ----------------
__global__ void scan_summary(const ushort_t* __restrict__ U, const float* __restrict__ bias,
                             float* __restrict__ Sa, float* __restrict__ Sb) {
    const int b = blockIdx.x / NCHUNK;
    const int chunk = blockIdx.x % NCHUNK;
    const int h = threadIdx.x << 2;
    float fb[4];
#pragma unroll
    for (int j = 0; j < 4; ++j) fb[j] = bias[h + j];
    float Aa[4] = {1.f, 1.f, 1.f, 1.f};
    float Bb[4] = {0.f, 0.f, 0.f, 0.f};
    const ushort_t* rp = U + ((size_t)(chunk * CLEN) * B_DIM + b) * N3H + h;
    ushort4 xt = *reinterpret_cast<const ushort4*>(rp);
    ushort4 fp = *reinterpret_cast<const ushort4*>(rp + H_DIM);
#pragma unroll
    for (int s = 0; s < CLEN; ++s) {
        ushort4 xt_n, fp_n;
        if (s + 1 < CLEN) {
            rp += (size_t)B_DIM * N3H;
            xt_n = *reinterpret_cast<const ushort4*>(rp);
            fp_n = *reinterpret_cast<const ushort4*>(rp + H_DIM);
        }
        float xs[4] = {bf2f(xt.x), bf2f(xt.y), bf2f(xt.z), bf2f(xt.w)};
        float fs[4] = {bf2f(fp.x), bf2f(fp.y), bf2f(fp.z), bf2f(fp.w)};
#pragma unroll
        for (int j = 0; j < 4; ++j) {
            float f = sigm(fs[j] + fb[j]);
            Aa[j] *= f;
            Bb[j] = f * Bb[j] + (1.f - f) * xs[j];
        }
        xt = xt_n; fp = fp_n;
    }
    const int cb = chunk * NCHAIN + b * H_DIM + h;
#pragma unroll
    for (int j = 0; j < 4; ++j) { Sa[cb + j] = Aa[j]; Sb[cb + j] = Bb[j]; }
}

// ---------------- scan pass B1: per-group local exclusive prefixes (in-place) + group summaries ----------------
__global__ void scan_fixup1(float* Sa, float* Sb, float* __restrict__ Ga, float* __restrict__ Gb) {
    const int idx = blockIdx.x * blockDim.x + threadIdx.x;   // NGRP*4096
    const int chain = idx & (NCHAIN - 1);
    const int g = idx >> 12;
    float A = 1.f, B = 0.f;
#pragma unroll
    for (int i = 0; i < GLEN; ++i) {
        const size_t off = (size_t)(g * GLEN + i) * NCHAIN + chain;
        float a = Sa[off], b = Sb[off];
        Sa[off] = A; Sb[off] = B;       // exclusive prefix (read-before-write, thread-owned)
        B = a * B + b;
        A = a * A;
    }
    Ga[g * NCHAIN + chain] = A;
    Gb[g * NCHAIN + chain] = B;
}

// ---------------- scan pass B2: scan group summaries -> group-entry states ----------------
__global__ void scan_fixup2(const float* __restrict__ Ga, const float* __restrict__ Gb,
                            float* __restrict__ Eg, float* __restrict__ clast) {
    const int chain = blockIdx.x * blockDim.x + threadIdx.x;  // 4096
    float c = 0.f;
#pragma unroll
    for (int g = 0; g < NGRP; ++g) {
        Eg[g * NCHAIN + chain] = c;
        c = Ga[g * NCHAIN + chain] * c + Gb[g * NCHAIN + chain];
    }
    if (clast) clast[chain] = c;   // chain = b*H + h -> [B][H]
}

// ---------------- scan pass C: apply with reconstructed entry c + highway epilogue ----------------
template <bool IN_BF16, bool OUT_BF16>
__global__ void scan_apply(const ushort_t* __restrict__ U, const float* __restrict__ bias,
                           const float* __restrict__ Sa, const float* __restrict__ Sb,
                           const float* __restrict__ Eg,
                           const void* __restrict__ xin, void* __restrict__ hout) {
    const int b = blockIdx.x / NCHUNK;
    const int chunk = blockIdx.x % NCHUNK;
    const int h = threadIdx.x << 2;
    const int cb = chunk * NCHAIN + b * H_DIM + h;
    const int eb = (chunk >> 4) * NCHAIN + b * H_DIM + h;   // group (GLEN=16) of this chunk
    float cc[4], fb[4], rb[4];
    float4 la = *reinterpret_cast<const float4*>(&Sa[cb]);
    float4 lb = *reinterpret_cast<const float4*>(&Sb[cb]);
    float4 eg = *reinterpret_cast<const float4*>(&Eg[eb]);
    cc[0] = lb.x + la.x * eg.x; cc[1] = lb.y + la.y * eg.y;
    cc[2] = lb.z + la.z * eg.z; cc[3] = lb.w + la.w * eg.w;
#pragma unroll
    for (int j = 0; j < 4; ++j) {
        fb[j] = bias[h + j];
        rb[j] = bias[H_DIM + h + j];
    }
    size_t row = (size_t)(chunk * CLEN) * B_DIM + b;
    const ushort_t* rp = U + row * N3H + h;
    size_t xoff = row * H_DIM + h;

    ushort4 xt = *reinterpret_cast<const ushort4*>(rp);
    ushort4 fp = *reinterpret_cast<const ushort4*>(rp + H_DIM);
    ushort4 rr = *reinterpret_cast<const ushort4*>(rp + 2 * H_DIM);
    float xv[4];
    if (IN_BF16) {
        ushort4 xi = *reinterpret_cast<const ushort4*>((const ushort_t*)xin + xoff);
        xv[0] = bf2f(xi.x); xv[1] = bf2f(xi.y); xv[2] = bf2f(xi.z); xv[3] = bf2f(xi.w);
    } else {
        float4 xi = *reinterpret_cast<const float4*>((const float*)xin + xoff);
        xv[0] = xi.x; xv[1] = xi.y; xv[2] = xi.z; xv[3] = xi.w;
    }

#pragma unroll
    for (int s = 0; s < CLEN; ++s) {
        ushort4 xt_n, fp_n, rr_n;
        float xv_n[4];
        if (s + 1 < CLEN) {
            rp += (size_t)B_DIM * N3H;
            xt_n = *reinterpret_cast<const ushort4*>(rp);
            fp_n = *reinterpret_cast<const ushort4*>(rp + H_DIM);
            rr_n = *reinterpret_cast<const ushort4*>(rp + 2 * H_DIM);
            size_t xo2 = xoff + (size_t)B_DIM * H_DIM;
            if (IN_BF16) {
                ushort4 xi = *reinterpret_cast<const ushort4*>((const ushort_t*)xin + xo2);
                xv_n[0] = bf2f(xi.x); xv_n[1] = bf2f(xi.y); xv_n[2] = bf2f(xi.z); xv_n[3] = bf2f(xi.w);
            } else {
                float4 xi = *reinterpret_cast<const float4*>((const float*)xin + xo2);
                xv_n[0] = xi.x; xv_n[1] = xi.y; xv_n[2] = xi.z; xv_n[3] = xi.w;
            }
        }
        float xts[4] = {bf2f(xt.x), bf2f(xt.y), bf2f(xt.z), bf2f(xt.w)};
        float fps[4] = {bf2f(fp.x), bf2f(fp.y), bf2f(fp.z), bf2f(fp.w)};
        float rps[4] = {bf2f(rr.x), bf2f(rr.y), bf2f(rr.z), bf2f(rr.w)};
        float hv[4];
#pragma unroll
        for (int j = 0; j < 4; ++j) {
            float f = sigm(fps[j] + fb[j]);
            cc[j] = f * cc[j] + (1.f - f) * xts[j];
            float r = sigm(rps[j] + rb[j]);
            hv[j] = r * tanh_fast(cc[j]) + (1.f - r) * xv[j];
        }
        if (OUT_BF16) {
            ushort4 o;
            o.x = f2bf(hv[0]); o.y = f2bf(hv[1]); o.z = f2bf(hv[2]); o.w = f2bf(hv[3]);
            *reinterpret_cast<ushort4*>((ushort_t*)hout + xoff) = o;
        } else {
            float4 o;
            o.x = hv[0]; o.y = hv[1]; o.z = hv[2]; o.w = hv[3];
            *reinterpret_cast<float4*>((float*)hout + xoff) = o;
        }
        xoff += (size_t)B_DIM * H_DIM;
        xt = xt_n; fp = fp_n; rr = rr_n;
        xv[0] = xv_n[0]; xv[1] = xv_n[1]; xv[2] = xv_n[2]; xv[3] = xv_n[3];
    }
}

extern "C" void kernel_launch(void* const* d_in, const int* in_sizes, int n_in,
                              void* d_out, int out_size, void* d_ws, size_t ws_size,
                              hipStream_t stream) {
    (void)in_sizes; (void)n_in; (void)out_size; (void)ws_size;
    const float* x  = (const float*)d_in[0];   // [T,B,512]
    const float* W0 = (const float*)d_in[1];   // [1536,512]
    const float* b0 = (const float*)d_in[2];   // [1024]
    const float* W1 = (const float*)d_in[3];   // [1536,512]
    const float* b1 = (const float*)d_in[4];   // [1024]
    float* out = (float*)d_out;                // h [T,B,512] fp32, then c_last [B,512] fp32

    // ws layout (bytes); total 163 MiB.
    // [0,32M): xb (bf16 x) -- dead after GEMM1; Sa/Sb/Ga/Gb/Eg alias here afterwards
    char* ws = (char*)d_ws;
    ushort_t* xb  = (ushort_t*)(ws);
    float*    Sa  = (float*)(ws);                 // 8 MiB
    float*    Sb  = (float*)(ws + 8388608);       // 8 MiB
    float*    Ga  = (float*)(ws + 16777216);      // 512 KiB
    float*    Gb  = (float*)(ws + 17301504);      // 512 KiB
    float*    Eg  = (float*)(ws + 17825792);      // 512 KiB
    ushort_t* h1  = (ushort_t*)(ws + 33554432);   // 32 MiB
    ushort_t* W0b = (ushort_t*)(ws + 67108864);   // 1.5 MiB
    ushort_t* W1b = (ushort_t*)(ws + 68681728);   // 1.5 MiB
    ushort_t* U   = (ushort_t*)(ws + 70254592);   // 96 MiB

    const int cvt_total = XF4 + 2 * WF4;
    cvt_all<<<(cvt_total + 255) / 256, 256, 0, stream>>>(x, W0, W1, xb, W0b, W1b);

    const int gemm_grid = (M_DIM / 256) * (N3H / 256);   // 768 (%8==0)
    const int scan_grid = B_DIM * NCHUNK;                 // 4096

    // ---- layer 1 ----
    gemm_bt256<<<gemm_grid, 512, 0, stream>>>(xb, W0b, U, M_DIM, N3H, K_DIM);
    scan_summary<<<scan_grid, 128, 0, stream>>>(U, b0, Sa, Sb);
    scan_fixup1<<<NGRP * NCHAIN / 256, 256, 0, stream>>>(Sa, Sb, Ga, Gb);
    scan_fixup2<<<NCHAIN / 256, 256, 0, stream>>>(Ga, Gb, Eg, nullptr);
    scan_apply<false, true><<<scan_grid, 128, 0, stream>>>(U, b0, Sa, Sb, Eg, (const void*)x, (void*)h1);

    // ---- layer 2 ----
    gemm_bt256<<<gemm_grid, 512, 0, stream>>>(h1, W1b, U, M_DIM, N3H, K_DIM);
    scan_summary<<<scan_grid, 128, 0, stream>>>(U, b1, Sa, Sb);
    scan_fixup1<<<NGRP * NCHAIN / 256, 256, 0, stream>>>(Sa, Sb, Ga, Gb);
    scan_fixup2<<<NCHAIN / 256, 256, 0, stream>>>(Ga, Gb, Eg, out + (size_t)M_DIM * H_DIM);
    scan_apply<true, false><<<scan_grid, 128, 0, stream>>>(U, b1, Sa, Sb, Eg, (const void*)h1, (void*)out);
}